// Round 2
// baseline (830.511 us; speedup 1.0000x reference)
//
#include <hip/hip_runtime.h>
#include <hip/hip_bf16.h>

// Problem constants
#define T_TOK 4096
#define DDIM  2048
#define IDIM  1024
#define NEXP  8
#define NPAIR 8192    // T_TOK * top_k
#define TPAIR 12288   // NPAIR + T_TOK shared rows

typedef unsigned short u16;
typedef __bf16 bf16x8 __attribute__((ext_vector_type(8)));
typedef float  f32x4  __attribute__((ext_vector_type(4)));
typedef unsigned short u16x4 __attribute__((ext_vector_type(4)));
typedef unsigned short u16x8 __attribute__((ext_vector_type(8)));

__device__ __forceinline__ u16 f2bf(float f) {
  union { float f; unsigned u; } v; v.f = f;
  unsigned r = v.u + 0x7fffu + ((v.u >> 16) & 1u);   // RNE
  return (u16)(r >> 16);
}

// async global->LDS, 16B per lane; LDS dest is wave-uniform base (+lane*16 by HW)
__device__ __forceinline__ void gll16(const void* g, void* l) {
  __builtin_amdgcn_global_load_lds(
      (__attribute__((address_space(1))) void*)(g),
      (__attribute__((address_space(3))) void*)(l),
      16, 0, 0);
}

// ---------------- router: logits = x @ rw (fp64 accum), top-2, sigmoid ----------------
__global__ __launch_bounds__(256)
void router_kernel(const float* __restrict__ x, const float* __restrict__ rw,
                   int* __restrict__ top_idx, float* __restrict__ top_w,
                   int* __restrict__ counts) {
  int t = blockIdx.x;
  int tid = threadIdx.x;
  int lane = tid & 63, wave = tid >> 6;
  const float* xr = x + (size_t)t * DDIM;
  double acc[NEXP];
#pragma unroll
  for (int e = 0; e < NEXP; ++e) acc[e] = 0.0;
  for (int d = tid; d < DDIM; d += 256) {
    double xv = (double)xr[d];
    const float* r = rw + (size_t)d * NEXP;
#pragma unroll
    for (int e = 0; e < NEXP; ++e) acc[e] += xv * (double)r[e];
  }
  __shared__ double wred[4][NEXP];
#pragma unroll
  for (int e = 0; e < NEXP; ++e) {
    double v = acc[e];
    for (int s = 32; s > 0; s >>= 1) v += __shfl_down(v, s);
    if (lane == 0) wred[wave][e] = v;
  }
  __syncthreads();
  if (tid == 0) {
    float lg[NEXP];
#pragma unroll
    for (int e = 0; e < NEXP; ++e)
      lg[e] = (float)(wred[0][e] + wred[1][e] + wred[2][e] + wred[3][e]);
    int e0 = 0; float v0 = lg[0];
    for (int e = 1; e < NEXP; ++e) if (lg[e] > v0) { v0 = lg[e]; e0 = e; }
    int e1 = -1; float v1 = -3.4e38f;
    for (int e = 0; e < NEXP; ++e) if (e != e0 && lg[e] > v1) { v1 = lg[e]; e1 = e; }
    float p0 = 1.0f / (1.0f + __expf(-v0));
    float p1 = 1.0f / (1.0f + __expf(-v1));
    top_idx[t * 2 + 0] = e0; top_idx[t * 2 + 1] = e1;
    top_w[t * 2 + 0] = p0;  top_w[t * 2 + 1] = p1;
    atomicAdd(&counts[e0], 1);
    atomicAdd(&counts[e1], 1);
  }
}

__global__ void init_kernel(int* counts) {
  if (threadIdx.x < NEXP) counts[threadIdx.x] = 0;
}

// prefix sum over 8 routed experts + shared (e=8) row-tile table
__global__ void offsets_kernel(const int* __restrict__ counts, int* __restrict__ offs,
                               int* __restrict__ fill, int* __restrict__ tab,
                               int* __restrict__ ntl) {
  if (blockIdx.x == 0 && threadIdx.x == 0) {
    int off = 0, nt = 0;
    for (int e = 0; e < NEXP; ++e) {
      offs[e] = off;
      int c = counts[e];
      int tb = (c + 127) >> 7;
      for (int t = 0; t < tb; ++t) tab[nt++] = (e << 16) | t;
      off += c;
      fill[e] = 0;
    }
    offs[NEXP] = NPAIR;       // routed total is exactly NPAIR
    offs[NEXP + 1] = TPAIR;   // shared region
    for (int t = 0; t < 32; ++t) tab[nt++] = (NEXP << 16) | t;  // 4096/128 shared tiles
    *ntl = nt;
    for (int i = nt; i < 144; ++i) tab[i] = 0;
  }
}

__global__ __launch_bounds__(256)
void scatter_kernel(const int* __restrict__ top_idx, const float* __restrict__ top_w,
                    const int* __restrict__ offs, int* __restrict__ fill,
                    int* __restrict__ tlist, float* __restrict__ pw,
                    int* __restrict__ pos_of) {
  int t = blockIdx.x * blockDim.x + threadIdx.x;
  if (t >= T_TOK) return;
#pragma unroll
  for (int k = 0; k < 2; ++k) {
    int e = top_idx[t * 2 + k];
    float w = top_w[t * 2 + k];
    int pos = offs[e] + atomicAdd(&fill[e], 1);
    tlist[pos] = t;
    pw[pos] = w;
    pos_of[t * 2 + k] = pos;
  }
  tlist[NPAIR + t] = t;   // shared region: identity gather, weight 1
  pw[NPAIR + t] = 1.0f;
}

// ---------------- fp32 -> bf16 convert of x ----------------
__global__ __launch_bounds__(256)
void cvt_x_kernel(const float* __restrict__ in, u16* __restrict__ out) {
  size_t i = ((size_t)blockIdx.x * blockDim.x + threadIdx.x) * 4;
  float4 v = *(const float4*)(in + i);
  u16x4 o;
  o.x = f2bf(v.x); o.y = f2bf(v.y); o.z = f2bf(v.z); o.w = f2bf(v.w);
  *(u16x4*)(out + i) = o;
}

// ---------------- 64x64 fp32->bf16 transpose core ----------------
// inb: origin of 64(rows=K) x 64(cols=N) fp32 tile, row stride inRS floats
// outb: out + (first_out_row)*outRS2_base ... precomputed; per n the row advances outRS2 u16
__device__ __forceinline__ void t64_core(const float* __restrict__ inb, int inRS,
                                         u16* __restrict__ outb, int outRS2) {
  __shared__ float tile[64][65];
  int tid = threadIdx.x;
  int tx = tid & 15, ty = tid >> 4;
#pragma unroll
  for (int rr = 0; rr < 4; ++rr) {
    int r = ty + rr * 16;
    float4 v = *(const float4*)(inb + (size_t)r * inRS + tx * 4);
    tile[r][tx * 4 + 0] = v.x; tile[r][tx * 4 + 1] = v.y;
    tile[r][tx * 4 + 2] = v.z; tile[r][tx * 4 + 3] = v.w;
  }
  __syncthreads();
  int n = tid >> 2, c8 = tid & 3;
#pragma unroll
  for (int cc = 0; cc < 2; ++cc) {
    int k0 = (c8 + cc * 4) * 8;
    u16x8 o;
#pragma unroll
    for (int j = 0; j < 8; ++j) o[j] = f2bf(tile[k0 + j][n]);
    *(u16x8*)(outb + (size_t)n * outRS2 + k0) = o;
  }
}

// gate_up_w [E][D][2I] -> gut slab e: [2I][D], rows interleaved 2i+s
__global__ __launch_bounds__(256)
void t_gu_kernel(const float* __restrict__ in, u16* __restrict__ out) {
  int z = blockIdx.z, e = z >> 1, s = z & 1;
  int kt = blockIdx.x, nt = blockIdx.y;
  const float* inb = in + (size_t)e * DDIM * (2 * IDIM) + (size_t)(kt * 64) * (2 * IDIM)
                        + (size_t)s * IDIM + nt * 64;
  u16* outb = out + (size_t)e * (2 * IDIM) * DDIM + (size_t)(2 * (nt * 64) + s) * DDIM + kt * 64;
  t64_core(inb, 2 * IDIM, outb, 2 * DDIM);
}
// shared gate/up [D][I] -> gut slab 8, interleaved
__global__ __launch_bounds__(256)
void t_sgu_kernel(const float* __restrict__ sg, const float* __restrict__ su,
                  u16* __restrict__ out) {
  int s = blockIdx.z;
  const float* in = s ? su : sg;
  int kt = blockIdx.x, nt = blockIdx.y;
  const float* inb = in + (size_t)(kt * 64) * IDIM + nt * 64;
  u16* outb = out + (size_t)NEXP * (2 * IDIM) * DDIM + (size_t)(2 * (nt * 64) + s) * DDIM + kt * 64;
  t64_core(inb, IDIM, outb, 2 * DDIM);
}
// down_w [E][I][D] -> dwt slab e: [D][I]
__global__ __launch_bounds__(256)
void t_dw_kernel(const float* __restrict__ in, u16* __restrict__ out) {
  int e = blockIdx.z;
  int kt = blockIdx.x, nt = blockIdx.y;
  const float* inb = in + (size_t)e * IDIM * DDIM + (size_t)(kt * 64) * DDIM + nt * 64;
  u16* outb = out + (size_t)e * DDIM * IDIM + (size_t)(nt * 64) * IDIM + kt * 64;
  t64_core(inb, DDIM, outb, IDIM);
}
// shared_down [I][D] -> dwt slab 8
__global__ __launch_bounds__(256)
void t_sd_kernel(const float* __restrict__ in, u16* __restrict__ out) {
  int kt = blockIdx.x, nt = blockIdx.y;
  const float* inb = in + (size_t)(kt * 64) * DDIM + nt * 64;
  u16* outb = out + (size_t)NEXP * DDIM * IDIM + (size_t)(nt * 64) * IDIM + kt * 64;
  t64_core(inb, DDIM, outb, IDIM);
}

// ---------------- main tiled GEMM (m97 structure), 9-expert pair list ----------------
// GATEUP: A gathered via tlist; p pre-silu; interleaved gate/up combine -> bf16 h
// !GATEUP (down): A = h pair-major direct; plain store to dout pair rows
template <bool GATEUP>
__global__ __launch_bounds__(256)
void gemm_kernel(const u16* __restrict__ A, const u16* __restrict__ Bt,
                 float* __restrict__ outp, u16* __restrict__ hout,
                 const int* __restrict__ tab, const int* __restrict__ ntl,
                 const int* __restrict__ offs, const int* __restrict__ tlist,
                 const float* __restrict__ pw, int Kdim) {
  constexpr int BM = 128, BN = 128, BK = 32;
  __shared__ alignas(16) u16 Asm[BM * BK];
  __shared__ alignas(16) u16 Bsm[BN * BK];

  int bx = blockIdx.x, by = blockIdx.y;
  int nt = *ntl;
  if (bx >= nt) return;
  int tt = tab[bx];
  int e = tt >> 16;
  int rb = tt & 0xffff;
  int seg = offs[e];
  int mcnt = offs[e + 1] - seg;
  int m0 = rb * BM;
  int n0 = by * BN;
  const u16* Bte = Bt + (size_t)e * 2048 * (size_t)Kdim + (size_t)n0 * Kdim;

  int tid = threadIdx.x;
  int lane = tid & 63, wave = tid >> 6;
  int wm = (wave & 1) * 64, wn = (wave >> 1) * 64;

  int sr0 = wave * 16 + (lane >> 2);  // staged row (this thread), issue 0
  int colb = (lane & 3) * 8;          // element offset of this thread's 16B chunk

  const u16 *ap0, *ap1;
  {
    int g0 = m0 + sr0, g1 = m0 + sr0 + 64;
    if (g0 > mcnt - 1) g0 = mcnt - 1;
    if (g1 > mcnt - 1) g1 = mcnt - 1;
    if constexpr (GATEUP) {
      ap0 = A + (size_t)tlist[seg + g0] * Kdim;
      ap1 = A + (size_t)tlist[seg + g1] * Kdim;
    } else {
      ap0 = A + (size_t)(seg + g0) * Kdim;
      ap1 = A + (size_t)(seg + g1) * Kdim;
    }
  }
  const u16* bp0 = Bte + (size_t)sr0 * Kdim;
  const u16* bp1 = Bte + (size_t)(sr0 + 64) * Kdim;

  u16* As0 = Asm + (wave * 16) * BK;
  u16* As1 = Asm + (64 + wave * 16) * BK;
  u16* Bs0 = Bsm + (wave * 16) * BK;
  u16* Bs1 = Bsm + (64 + wave * 16) * BK;

  f32x4 acc[4][4] = {};

  for (int k0 = 0; k0 < Kdim; k0 += BK) {
    gll16(ap0 + k0 + colb, As0);
    gll16(ap1 + k0 + colb, As1);
    gll16(bp0 + k0 + colb, Bs0);
    gll16(bp1 + k0 + colb, Bs1);
    asm volatile("s_waitcnt vmcnt(0)" ::: "memory");
    __syncthreads();

    int kq = (lane >> 4) * 8;
    bf16x8 af[4], bfr[4];
#pragma unroll
    for (int t = 0; t < 4; ++t) {
      af[t]  = *(const bf16x8*)(Asm + (size_t)(wm + t * 16 + (lane & 15)) * BK + kq);
      bfr[t] = *(const bf16x8*)(Bsm + (size_t)(wn + t * 16 + (lane & 15)) * BK + kq);
    }
#pragma unroll
    for (int tm = 0; tm < 4; ++tm)
#pragma unroll
      for (int tn = 0; tn < 4; ++tn)
        acc[tm][tn] = __builtin_amdgcn_mfma_f32_16x16x32_bf16(af[tm], bfr[tn], acc[tm][tn], 0, 0, 0);
    __syncthreads();
  }

  // epilogue: C/D layout col = lane&15 (N), row = (lane>>4)*4 + r (M)
  int cn = lane & 15;
  int rq = (lane >> 4) * 4;

  if constexpr (GATEUP) {
#pragma unroll
    for (int tm = 0; tm < 4; ++tm) {
#pragma unroll
      for (int r = 0; r < 4; ++r) {
        int mloc = wm + tm * 16 + rq + r;
        int mg = m0 + mloc;
        bool valid = (mg < mcnt);
        int pi = seg + mg; if (pi > TPAIR - 1) pi = TPAIR - 1;
        float p = valid ? pw[pi] : 0.0f;
#pragma unroll
        for (int tn = 0; tn < 4; ++tn) {
          float v = acc[tm][tn][r] * p;       // p applied PRE-silu (matches reference)
          float o = __shfl_xor(v, 1);         // partner column (gate<->up)
          if (!(cn & 1) && valid) {
            float g = v, u = o;
            float h = (g / (1.0f + __expf(-g))) * u;   // silu(g)*u
            int nbase = n0 + wn + tn * 16;
            int i = (nbase >> 1) + (cn >> 1);
            hout[(size_t)(seg + mg) * IDIM + i] = f2bf(h);
          }
        }
      }
    }
  } else {
#pragma unroll
    for (int tm = 0; tm < 4; ++tm) {
#pragma unroll
      for (int r = 0; r < 4; ++r) {
        int mloc = wm + tm * 16 + rq + r;
        int mg = m0 + mloc;
        if (mg < mcnt) {
#pragma unroll
          for (int tn = 0; tn < 4; ++tn) {
            int n = n0 + wn + tn * 16 + cn;
            outp[(size_t)(seg + mg) * DDIM + n] = acc[tm][tn][r];
          }
        }
      }
    }
  }
}

// ---------------- final combine: out[t] = dout[p0] + dout[p1] + dout[shared_t] ----------------
__global__ __launch_bounds__(256)
void combine_kernel(const float* __restrict__ dout, const int* __restrict__ pos_of,
                    float* __restrict__ out) {
  int idx = blockIdx.x * 256 + threadIdx.x;
  int t = idx >> 9;              // 512 float4 per row
  int c = (idx & 511) * 4;
  int p0 = pos_of[t * 2];
  int p1 = pos_of[t * 2 + 1];
  float4 a = *(const float4*)(dout + (size_t)p0 * DDIM + c);
  float4 b = *(const float4*)(dout + (size_t)p1 * DDIM + c);
  float4 s = *(const float4*)(dout + (size_t)(NPAIR + t) * DDIM + c);
  float4 o;
  o.x = a.x + b.x + s.x; o.y = a.y + b.y + s.y;
  o.z = a.z + b.z + s.z; o.w = a.w + b.w + s.w;
  *(float4*)(out + (size_t)t * DDIM + c) = o;
}

// ---------------- launch ----------------
extern "C" void kernel_launch(void* const* d_in, const int* in_sizes, int n_in,
                              void* d_out, int out_size, void* d_ws, size_t ws_size,
                              hipStream_t stream) {
  const float* x   = (const float*)d_in[0];
  const float* rw  = (const float*)d_in[1];
  const float* guw = (const float*)d_in[2];
  const float* dw  = (const float*)d_in[3];
  const float* sgw = (const float*)d_in[4];
  const float* suw = (const float*)d_in[5];
  const float* sdw = (const float*)d_in[6];
  float* outp = (float*)d_out;
  (void)in_sizes; (void)n_in; (void)out_size; (void)ws_size;

  char* ws = (char*)d_ws;
  size_t off = 0;
  auto alloc = [&](size_t bytes) -> void* {
    void* p = ws + off;
    off += (bytes + 255) & ~(size_t)255;
    return p;
  };
  // region0: gut (75.5 MB) + xb (16.8 MB) during gateup; overlaid by dout (100.7 MB) for down
  const size_t gut_b  = (size_t)(NEXP + 1) * 2 * IDIM * DDIM * 2;   // 75.5 MB
  const size_t xb_b   = (size_t)T_TOK * DDIM * 2;                   // 16.8 MB
  const size_t dout_b = (size_t)TPAIR * DDIM * 4;                   // 100.7 MB
  char* region0 = (char*)alloc(dout_b > gut_b + xb_b ? dout_b : gut_b + xb_b);
  u16*   gut  = (u16*)region0;
  u16*   xb   = (u16*)(region0 + gut_b);
  float* dout = (float*)region0;

  u16* dwt = (u16*)alloc((size_t)(NEXP + 1) * DDIM * IDIM * 2);     // 37.75 MB
  u16* he  = (u16*)alloc((size_t)TPAIR * IDIM * 2);                 // 25.2 MB
  int* top_idx = (int*)alloc(T_TOK * 2 * 4);
  float* top_w = (float*)alloc(T_TOK * 2 * 4);
  int* counts  = (int*)alloc(NEXP * 4);
  int* offs    = (int*)alloc((NEXP + 2) * 4);
  int* fill    = (int*)alloc(NEXP * 4);
  int* tab     = (int*)alloc(144 * 4);
  int* ntl     = (int*)alloc(4);
  int* tlist   = (int*)alloc(TPAIR * 4);
  float* pw    = (float*)alloc(TPAIR * 4);
  int* pos_of  = (int*)alloc(NPAIR * 4);

  // routing
  init_kernel<<<dim3(1), dim3(64), 0, stream>>>(counts);
  router_kernel<<<dim3(T_TOK), dim3(256), 0, stream>>>(x, rw, top_idx, top_w, counts);
  offsets_kernel<<<dim3(1), dim3(1), 0, stream>>>(counts, offs, fill, tab, ntl);
  scatter_kernel<<<dim3(16), dim3(256), 0, stream>>>(top_idx, top_w, offs, fill, tlist, pw, pos_of);

  // fp32 -> bf16 (+transpose) pre-pass
  cvt_x_kernel<<<dim3(8192), dim3(256), 0, stream>>>(x, xb);
  t_gu_kernel<<<dim3(32, 16, 16), dim3(256), 0, stream>>>(guw, gut);
  t_sgu_kernel<<<dim3(32, 16, 2), dim3(256), 0, stream>>>(sgw, suw, gut);
  t_dw_kernel<<<dim3(16, 32, 8), dim3(256), 0, stream>>>(dw, dwt);
  t_sd_kernel<<<dim3(16, 32, 1), dim3(256), 0, stream>>>(sdw, dwt);

  // gateup over all 12288 pairs (routed + shared): he = silu(p*(x@Wg)) * (p*(x@Wu))
  gemm_kernel<true><<<dim3(103, 16), dim3(256), 0, stream>>>(
      xb, gut, nullptr, he, tab, ntl, offs, tlist, pw, DDIM);
  // down over all pairs: dout[pair] = he[pair] @ Wd   (overlays gut/xb — both dead now)
  gemm_kernel<false><<<dim3(103, 16), dim3(256), 0, stream>>>(
      he, dwt, dout, nullptr, tab, ntl, offs, tlist, pw, IDIM);

  // out[t] = dout[p0] + dout[p1] + dout[8192+t]
  combine_kernel<<<dim3(8192), dim3(256), 0, stream>>>(dout, pos_of, outp);
}

// Round 3
// 712.984 us; speedup vs baseline: 1.1648x; 1.1648x over previous
//
#include <hip/hip_runtime.h>
#include <hip/hip_bf16.h>

// Problem constants
#define T_TOK 4096
#define DDIM  2048
#define IDIM  1024
#define NEXP  8
#define NPAIR 8192    // T_TOK * top_k
#define TPAIR 12288   // NPAIR + T_TOK shared rows

typedef unsigned short u16;
typedef __bf16 bf16x8 __attribute__((ext_vector_type(8)));
typedef float  f32x4  __attribute__((ext_vector_type(4)));
typedef unsigned short u16x4 __attribute__((ext_vector_type(4)));
typedef unsigned short u16x8 __attribute__((ext_vector_type(8)));

__device__ __forceinline__ u16 f2bf(float f) {
  union { float f; unsigned u; } v; v.f = f;
  unsigned r = v.u + 0x7fffu + ((v.u >> 16) & 1u);   // RNE
  return (u16)(r >> 16);
}

// async global->LDS, 16B per lane; LDS dest is wave-uniform base (+lane*16 by HW)
__device__ __forceinline__ void gll16(const void* g, void* l) {
  __builtin_amdgcn_global_load_lds(
      (__attribute__((address_space(1))) void*)(g),
      (__attribute__((address_space(3))) void*)(l),
      16, 0, 0);
}

// ---------------- router: logits = x @ rw (fp64 accum), top-2, sigmoid ----------------
__global__ __launch_bounds__(256)
void router_kernel(const float* __restrict__ x, const float* __restrict__ rw,
                   int* __restrict__ top_idx, float* __restrict__ top_w,
                   int* __restrict__ counts) {
  int t = blockIdx.x;
  int tid = threadIdx.x;
  int lane = tid & 63, wave = tid >> 6;
  const float* xr = x + (size_t)t * DDIM;
  double acc[NEXP];
#pragma unroll
  for (int e = 0; e < NEXP; ++e) acc[e] = 0.0;
  for (int d = tid; d < DDIM; d += 256) {
    double xv = (double)xr[d];
    const float* r = rw + (size_t)d * NEXP;
#pragma unroll
    for (int e = 0; e < NEXP; ++e) acc[e] += xv * (double)r[e];
  }
  __shared__ double wred[4][NEXP];
#pragma unroll
  for (int e = 0; e < NEXP; ++e) {
    double v = acc[e];
    for (int s = 32; s > 0; s >>= 1) v += __shfl_down(v, s);
    if (lane == 0) wred[wave][e] = v;
  }
  __syncthreads();
  if (tid == 0) {
    float lg[NEXP];
#pragma unroll
    for (int e = 0; e < NEXP; ++e)
      lg[e] = (float)(wred[0][e] + wred[1][e] + wred[2][e] + wred[3][e]);
    int e0 = 0; float v0 = lg[0];
    for (int e = 1; e < NEXP; ++e) if (lg[e] > v0) { v0 = lg[e]; e0 = e; }
    int e1 = -1; float v1 = -3.4e38f;
    for (int e = 0; e < NEXP; ++e) if (e != e0 && lg[e] > v1) { v1 = lg[e]; e1 = e; }
    float p0 = 1.0f / (1.0f + __expf(-v0));
    float p1 = 1.0f / (1.0f + __expf(-v1));
    top_idx[t * 2 + 0] = e0; top_idx[t * 2 + 1] = e1;
    top_w[t * 2 + 0] = p0;  top_w[t * 2 + 1] = p1;
    atomicAdd(&counts[e0], 1);
    atomicAdd(&counts[e1], 1);
  }
}

__global__ void init_kernel(int* counts) {
  if (threadIdx.x < NEXP) counts[threadIdx.x] = 0;
}

// prefix sum over 8 routed experts + shared (e=8) row-tile table
__global__ void offsets_kernel(const int* __restrict__ counts, int* __restrict__ offs,
                               int* __restrict__ fill, int* __restrict__ tab,
                               int* __restrict__ ntl) {
  if (blockIdx.x == 0 && threadIdx.x == 0) {
    int off = 0, nt = 0;
    for (int e = 0; e < NEXP; ++e) {
      offs[e] = off;
      int c = counts[e];
      int tb = (c + 127) >> 7;
      for (int t = 0; t < tb; ++t) tab[nt++] = (e << 16) | t;
      off += c;
      fill[e] = 0;
    }
    offs[NEXP] = NPAIR;       // routed total is exactly NPAIR
    offs[NEXP + 1] = TPAIR;   // shared region
    for (int t = 0; t < 32; ++t) tab[nt++] = (NEXP << 16) | t;  // 4096/128 shared tiles
    *ntl = nt;
    for (int i = nt; i < 144; ++i) tab[i] = 0;
  }
}

__global__ __launch_bounds__(256)
void scatter_kernel(const int* __restrict__ top_idx, const float* __restrict__ top_w,
                    const int* __restrict__ offs, int* __restrict__ fill,
                    int* __restrict__ tlist, float* __restrict__ pw,
                    int* __restrict__ pos_of) {
  int t = blockIdx.x * blockDim.x + threadIdx.x;
  if (t >= T_TOK) return;
#pragma unroll
  for (int k = 0; k < 2; ++k) {
    int e = top_idx[t * 2 + k];
    float w = top_w[t * 2 + k];
    int pos = offs[e] + atomicAdd(&fill[e], 1);
    tlist[pos] = t;
    pw[pos] = w;
    pos_of[t * 2 + k] = pos;
  }
  tlist[NPAIR + t] = t;   // shared region: identity gather, weight 1
  pw[NPAIR + t] = 1.0f;
}

// ---------------- fp32 -> bf16 convert of x ----------------
__global__ __launch_bounds__(256)
void cvt_x_kernel(const float* __restrict__ in, u16* __restrict__ out) {
  size_t i = ((size_t)blockIdx.x * blockDim.x + threadIdx.x) * 4;
  float4 v = *(const float4*)(in + i);
  u16x4 o;
  o.x = f2bf(v.x); o.y = f2bf(v.y); o.z = f2bf(v.z); o.w = f2bf(v.w);
  *(u16x4*)(out + i) = o;
}

// ---------------- 64x64 fp32->bf16 transpose core ----------------
__device__ __forceinline__ void t64_core(const float* __restrict__ inb, int inRS,
                                         u16* __restrict__ outb, int outRS2) {
  __shared__ float tile[64][65];
  int tid = threadIdx.x;
  int tx = tid & 15, ty = tid >> 4;
#pragma unroll
  for (int rr = 0; rr < 4; ++rr) {
    int r = ty + rr * 16;
    float4 v = *(const float4*)(inb + (size_t)r * inRS + tx * 4);
    tile[r][tx * 4 + 0] = v.x; tile[r][tx * 4 + 1] = v.y;
    tile[r][tx * 4 + 2] = v.z; tile[r][tx * 4 + 3] = v.w;
  }
  __syncthreads();
  int n = tid >> 2, c8 = tid & 3;
#pragma unroll
  for (int cc = 0; cc < 2; ++cc) {
    int k0 = (c8 + cc * 4) * 8;
    u16x8 o;
#pragma unroll
    for (int j = 0; j < 8; ++j) o[j] = f2bf(tile[k0 + j][n]);
    *(u16x8*)(outb + (size_t)n * outRS2 + k0) = o;
  }
}

// gate_up_w [E][D][2I] -> gut slab e: [2I][D], rows interleaved 2i+s
__global__ __launch_bounds__(256)
void t_gu_kernel(const float* __restrict__ in, u16* __restrict__ out) {
  int z = blockIdx.z, e = z >> 1, s = z & 1;
  int kt = blockIdx.x, nt = blockIdx.y;
  const float* inb = in + (size_t)e * DDIM * (2 * IDIM) + (size_t)(kt * 64) * (2 * IDIM)
                        + (size_t)s * IDIM + nt * 64;
  u16* outb = out + (size_t)e * (2 * IDIM) * DDIM + (size_t)(2 * (nt * 64) + s) * DDIM + kt * 64;
  t64_core(inb, 2 * IDIM, outb, 2 * DDIM);
}
// shared gate/up [D][I] -> gut slab 8, interleaved
__global__ __launch_bounds__(256)
void t_sgu_kernel(const float* __restrict__ sg, const float* __restrict__ su,
                  u16* __restrict__ out) {
  int s = blockIdx.z;
  const float* in = s ? su : sg;
  int kt = blockIdx.x, nt = blockIdx.y;
  const float* inb = in + (size_t)(kt * 64) * IDIM + nt * 64;
  u16* outb = out + (size_t)NEXP * (2 * IDIM) * DDIM + (size_t)(2 * (nt * 64) + s) * DDIM + kt * 64;
  t64_core(inb, IDIM, outb, 2 * DDIM);
}
// down_w [E][I][D] -> dwt slab e: [D][I]
__global__ __launch_bounds__(256)
void t_dw_kernel(const float* __restrict__ in, u16* __restrict__ out) {
  int e = blockIdx.z;
  int kt = blockIdx.x, nt = blockIdx.y;
  const float* inb = in + (size_t)e * IDIM * DDIM + (size_t)(kt * 64) * DDIM + nt * 64;
  u16* outb = out + (size_t)e * DDIM * IDIM + (size_t)(nt * 64) * IDIM + kt * 64;
  t64_core(inb, DDIM, outb, IDIM);
}
// shared_down [I][D] -> dwt slab 8
__global__ __launch_bounds__(256)
void t_sd_kernel(const float* __restrict__ in, u16* __restrict__ out) {
  int kt = blockIdx.x, nt = blockIdx.y;
  const float* inb = in + (size_t)(kt * 64) * DDIM + nt * 64;
  u16* outb = out + (size_t)NEXP * DDIM * IDIM + (size_t)(nt * 64) * IDIM + kt * 64;
  t64_core(inb, DDIM, outb, IDIM);
}

// ---------------- main tiled GEMM, swizzled 1-D grid + LDS double-buffer ----------------
// grid: bid = tile*16 + col, col fastest => concurrent blocks share A-tile & expert B-slab
// K-loop: single barrier per iter; next tile's global_load_lds issued before MFMA
template <bool GATEUP>
__global__ __launch_bounds__(256)
void gemm_kernel(const u16* __restrict__ A, const u16* __restrict__ Bt,
                 float* __restrict__ outp, u16* __restrict__ hout,
                 const int* __restrict__ tab, const int* __restrict__ ntl,
                 const int* __restrict__ offs, const int* __restrict__ tlist,
                 const float* __restrict__ pw, int Kdim) {
  constexpr int BM = 128, BN = 128, BK = 32;
  __shared__ alignas(16) u16 Asm[2][BM * BK];
  __shared__ alignas(16) u16 Bsm[2][BN * BK];

  int bid = blockIdx.x;
  int bx = bid >> 4;        // tile index (slow)
  int by = bid & 15;        // N column (fast)
  int nt = *ntl;
  if (bx >= nt) return;
  int tt = tab[bx];
  int e = tt >> 16;
  int rb = tt & 0xffff;
  int seg = offs[e];
  int mcnt = offs[e + 1] - seg;
  int m0 = rb * BM;
  int n0 = by * BN;
  const u16* Bte = Bt + (size_t)e * 2048 * (size_t)Kdim + (size_t)n0 * Kdim;

  int tid = threadIdx.x;
  int lane = tid & 63, wave = tid >> 6;
  int wm = (wave & 1) * 64, wn = (wave >> 1) * 64;

  int sr0 = wave * 16 + (lane >> 2);  // staged row (this thread)
  int colb = (lane & 3) * 8;          // element offset of this thread's 16B chunk

  const u16 *ap0, *ap1;
  {
    int g0 = m0 + sr0, g1 = m0 + sr0 + 64;
    if (g0 > mcnt - 1) g0 = mcnt - 1;
    if (g1 > mcnt - 1) g1 = mcnt - 1;
    if constexpr (GATEUP) {
      ap0 = A + (size_t)tlist[seg + g0] * Kdim;
      ap1 = A + (size_t)tlist[seg + g1] * Kdim;
    } else {
      ap0 = A + (size_t)(seg + g0) * Kdim;
      ap1 = A + (size_t)(seg + g1) * Kdim;
    }
  }
  const u16* bp0 = Bte + (size_t)sr0 * Kdim;
  const u16* bp1 = Bte + (size_t)(sr0 + 64) * Kdim;

  int lo0 = (wave * 16) * BK;
  int lo1 = (64 + wave * 16) * BK;

  auto stage = [&](int k0, int b) {
    gll16(ap0 + k0 + colb, Asm[b] + lo0);
    gll16(ap1 + k0 + colb, Asm[b] + lo1);
    gll16(bp0 + k0 + colb, Bsm[b] + lo0);
    gll16(bp1 + k0 + colb, Bsm[b] + lo1);
  };

  f32x4 acc[4][4] = {};
  int nIter = Kdim / BK;
  stage(0, 0);

  for (int it = 0; it < nIter; ++it) {
    int c = it & 1;
    asm volatile("s_waitcnt vmcnt(0)" ::: "memory");
    __syncthreads();                       // buf c staged; buf c^1 fully consumed
    if (it + 1 < nIter) stage((it + 1) * BK, c ^ 1);   // overlap with MFMA below

    int kq = (lane >> 4) * 8;
    bf16x8 af[4], bfr[4];
#pragma unroll
    for (int t = 0; t < 4; ++t) {
      af[t]  = *(const bf16x8*)(Asm[c] + (size_t)(wm + t * 16 + (lane & 15)) * BK + kq);
      bfr[t] = *(const bf16x8*)(Bsm[c] + (size_t)(wn + t * 16 + (lane & 15)) * BK + kq);
    }
#pragma unroll
    for (int tm = 0; tm < 4; ++tm)
#pragma unroll
      for (int tn = 0; tn < 4; ++tn)
        acc[tm][tn] = __builtin_amdgcn_mfma_f32_16x16x32_bf16(af[tm], bfr[tn], acc[tm][tn], 0, 0, 0);
  }

  // epilogue: C/D layout col = lane&15 (N), row = (lane>>4)*4 + r (M)
  int cn = lane & 15;
  int rq = (lane >> 4) * 4;

  if constexpr (GATEUP) {
#pragma unroll
    for (int tm = 0; tm < 4; ++tm) {
#pragma unroll
      for (int r = 0; r < 4; ++r) {
        int mloc = wm + tm * 16 + rq + r;
        int mg = m0 + mloc;
        bool valid = (mg < mcnt);
        int pi = seg + mg; if (pi > TPAIR - 1) pi = TPAIR - 1;
        float p = valid ? pw[pi] : 0.0f;
#pragma unroll
        for (int tn = 0; tn < 4; ++tn) {
          float v = acc[tm][tn][r] * p;       // p applied PRE-silu (matches reference)
          float o = __shfl_xor(v, 1);         // partner column (gate<->up)
          if (!(cn & 1) && valid) {
            float g = v, u = o;
            float h = (g / (1.0f + __expf(-g))) * u;   // silu(g)*u
            int nbase = n0 + wn + tn * 16;
            int i = (nbase >> 1) + (cn >> 1);
            hout[(size_t)(seg + mg) * IDIM + i] = f2bf(h);
          }
        }
      }
    }
  } else {
#pragma unroll
    for (int tm = 0; tm < 4; ++tm) {
#pragma unroll
      for (int r = 0; r < 4; ++r) {
        int mloc = wm + tm * 16 + rq + r;
        int mg = m0 + mloc;
        if (mg < mcnt) {
#pragma unroll
          for (int tn = 0; tn < 4; ++tn) {
            int n = n0 + wn + tn * 16 + cn;
            outp[(size_t)(seg + mg) * DDIM + n] = acc[tm][tn][r];
          }
        }
      }
    }
  }
}

// ---------------- final combine: out[t] = dout[p0] + dout[p1] + dout[shared_t] ----------------
__global__ __launch_bounds__(256)
void combine_kernel(const float* __restrict__ dout, const int* __restrict__ pos_of,
                    float* __restrict__ out) {
  int idx = blockIdx.x * 256 + threadIdx.x;
  int t = idx >> 9;              // 512 float4 per row
  int c = (idx & 511) * 4;
  int p0 = pos_of[t * 2];
  int p1 = pos_of[t * 2 + 1];
  float4 a = *(const float4*)(dout + (size_t)p0 * DDIM + c);
  float4 b = *(const float4*)(dout + (size_t)p1 * DDIM + c);
  float4 s = *(const float4*)(dout + (size_t)(NPAIR + t) * DDIM + c);
  float4 o;
  o.x = a.x + b.x + s.x; o.y = a.y + b.y + s.y;
  o.z = a.z + b.z + s.z; o.w = a.w + b.w + s.w;
  *(float4*)(out + (size_t)t * DDIM + c) = o;
}

// ---------------- launch ----------------
extern "C" void kernel_launch(void* const* d_in, const int* in_sizes, int n_in,
                              void* d_out, int out_size, void* d_ws, size_t ws_size,
                              hipStream_t stream) {
  const float* x   = (const float*)d_in[0];
  const float* rw  = (const float*)d_in[1];
  const float* guw = (const float*)d_in[2];
  const float* dw  = (const float*)d_in[3];
  const float* sgw = (const float*)d_in[4];
  const float* suw = (const float*)d_in[5];
  const float* sdw = (const float*)d_in[6];
  float* outp = (float*)d_out;
  (void)in_sizes; (void)n_in; (void)out_size; (void)ws_size;

  char* ws = (char*)d_ws;
  size_t off = 0;
  auto alloc = [&](size_t bytes) -> void* {
    void* p = ws + off;
    off += (bytes + 255) & ~(size_t)255;
    return p;
  };
  // region0: gut (75.5 MB) + xb (16.8 MB) during gateup; overlaid by dout (100.7 MB) for down
  const size_t gut_b  = (size_t)(NEXP + 1) * 2 * IDIM * DDIM * 2;   // 75.5 MB
  const size_t xb_b   = (size_t)T_TOK * DDIM * 2;                   // 16.8 MB
  const size_t dout_b = (size_t)TPAIR * DDIM * 4;                   // 100.7 MB
  char* region0 = (char*)alloc(dout_b > gut_b + xb_b ? dout_b : gut_b + xb_b);
  u16*   gut  = (u16*)region0;
  u16*   xb   = (u16*)(region0 + gut_b);
  float* dout = (float*)region0;

  u16* dwt = (u16*)alloc((size_t)(NEXP + 1) * DDIM * IDIM * 2);     // 37.75 MB
  u16* he  = (u16*)alloc((size_t)TPAIR * IDIM * 2);                 // 25.2 MB
  int* top_idx = (int*)alloc(T_TOK * 2 * 4);
  float* top_w = (float*)alloc(T_TOK * 2 * 4);
  int* counts  = (int*)alloc(NEXP * 4);
  int* offs    = (int*)alloc((NEXP + 2) * 4);
  int* fill    = (int*)alloc(NEXP * 4);
  int* tab     = (int*)alloc(144 * 4);
  int* ntl     = (int*)alloc(4);
  int* tlist   = (int*)alloc(TPAIR * 4);
  float* pw    = (float*)alloc(TPAIR * 4);
  int* pos_of  = (int*)alloc(NPAIR * 4);

  // routing
  init_kernel<<<dim3(1), dim3(64), 0, stream>>>(counts);
  router_kernel<<<dim3(T_TOK), dim3(256), 0, stream>>>(x, rw, top_idx, top_w, counts);
  offsets_kernel<<<dim3(1), dim3(1), 0, stream>>>(counts, offs, fill, tab, ntl);
  scatter_kernel<<<dim3(16), dim3(256), 0, stream>>>(top_idx, top_w, offs, fill, tlist, pw, pos_of);

  // fp32 -> bf16 (+transpose) pre-pass
  cvt_x_kernel<<<dim3(8192), dim3(256), 0, stream>>>(x, xb);
  t_gu_kernel<<<dim3(32, 16, 16), dim3(256), 0, stream>>>(guw, gut);
  t_sgu_kernel<<<dim3(32, 16, 2), dim3(256), 0, stream>>>(sgw, suw, gut);
  t_dw_kernel<<<dim3(16, 32, 8), dim3(256), 0, stream>>>(dw, dwt);
  t_sd_kernel<<<dim3(16, 32, 1), dim3(256), 0, stream>>>(sdw, dwt);

  // gateup over all 12288 pairs (routed + shared): he = silu(p*(x@Wg)) * (p*(x@Wu))
  gemm_kernel<true><<<dim3(103 * 16), dim3(256), 0, stream>>>(
      xb, gut, nullptr, he, tab, ntl, offs, tlist, pw, DDIM);
  // down over all pairs: dout[pair] = he[pair] @ Wd   (overlays gut/xb — both dead now)
  gemm_kernel<false><<<dim3(103 * 16), dim3(256), 0, stream>>>(
      he, dwt, dout, nullptr, tab, ntl, offs, tlist, pw, IDIM);

  // out[t] = dout[p0] + dout[p1] + dout[8192+t]
  combine_kernel<<<dim3(8192), dim3(256), 0, stream>>>(dout, pos_of, outp);
}